// Round 13
// baseline (207.378 us; speedup 1.0000x reference)
//
#include <hip/hip_runtime.h>
#include <hip/hip_fp16.h>
#include <math.h>

// SSL compressor gain: 128 independent nonlinear 2-state IIR chains, T=131072.
// Round 13: r12 minus the identified bug.
//   r12 post-mortem (1.3125): DECIMATED NEWTON converges to the decimated
//   trajectory's fixpoint, which is biased ~1 dB (relu-after-averaging:
//   E[relu] drops when sigma 12->6 under 4-sample averaging). Decimation is
//   only valid for the GUESS map (bias absorbed by exact Newton, r8-proven);
//   Newton must be exact (r12-refuted).
// Structure: 4x-decim map (K=16, SUB=16) -> per-row block (1024 thr, 4
// waves/SIMD): link-stage -> compose0 -> 3x EXACT Newton (jac CF=128 +
// affine LDS scan) -> exact out.
// Contraction: c ~ 0.11 @ CF=128 (r6: 0.43 @ CF=512, c prop CF); guess
// d0~1.3 -> d1~0.19 -> d2~0.004 -> floor.

constexpr int   T_LEN    = 131072;
constexpr int   NCM      = 64;              // coarse map chunks
constexpr int   CM       = T_LEN / NCM;     // 2048 samples
constexpr int   SUB      = 16;              // snapshots per map chunk (every 128)
constexpr int   NC       = NCM * SUB;       // 1024 fine chunks
constexpr int   CF       = T_LEN / NC;      // 128 samples
constexpr int   K        = 16;              // ES nodes: 0 .. -8, h=8/15
constexpr float STEP_ES  = 8.0f / 15.0f;
constexpr float INV_STEP = 15.0f / 8.0f;
constexpr int   DPF      = 8;               // float4 prefetch depth
constexpr int   NV_ROW   = T_LEN >> 2;
constexpr int   LINK     = NCM * K;         // 1024 link-table entries

// pw: 0 nhs, 1 hst, 2 nq, 3 r, 4..7 a_{af,as,sf,ss}, 8..11 a^4 (4x-decim),
//     12 nhs_q (= nhs/4)
__global__ void ssl_params_k(
        float* __restrict__ pw,
        const float* cth, const float* rl, const float* fbl,
        const float* uaf, const float* uas, const float* usf, const float* uss)
{
    const double FS = 44100.0;
    const double T_AF_MIN = 820.0 * 4.7e-07 * 0.8,   T_AF_MAX = 270000.0 * 4.7e-07 * 1.2;
    const double T_AS_MIN = 820.0 * 6.8e-06 * 0.8,   T_AS_MAX = 270000.0 * 6.8e-06 * 100.0;
    const double T_SF_MIN = 91000.0 * 4.7e-07 * 0.8, T_SF_MAX = 1200000.0 * 4.7e-07 * 1.2;
    const double T_SS_MIN = 750000.0 * 6.8e-06 * 0.8, T_SS_MAX = 750000.0 * 6.8e-06 * 100.0;

    double cr    = fmax(exp((double)rl[0]) + 1.0, 1.0 + 1e-4);
    double fb    = 1.0 / (1.0 + exp(-(double)fbl[0]));
    double slope = 1.0 - 1.0 / cr;

    double s_af = T_AF_MIN + (T_AF_MAX - T_AF_MIN) / (1.0 + exp(-(double)uaf[0]));
    double s_as = T_AS_MIN + (T_AS_MAX - T_AS_MIN) / (1.0 + exp(-(double)uas[0]));
    double s_sf = T_SF_MIN + (T_SF_MAX - T_SF_MIN) / (1.0 + exp(-(double)usf[0]));
    double s_ss = T_SS_MIN + (T_SS_MAX - T_SS_MIN) / (1.0 + exp(-(double)uss[0]));

    float a_af = (float)exp(-1.0 / (FS * s_af));
    float a_as = (float)exp(-1.0 / (FS * s_as));
    float a_sf = (float)exp(-1.0 / (FS * s_sf));
    float a_ss = (float)exp(-1.0 / (FS * s_ss));
    double q = 0.5 * slope * fb;

    pw[0]  = (float)(-0.5 * slope);
    pw[1]  = (float)(0.5 * slope * (double)cth[0]);
    pw[2]  = (float)(-q);
    pw[3]  = (float)(0.5 + q);
    pw[4]  = a_af;  pw[5] = a_as;  pw[6] = a_sf;  pw[7] = a_ss;
    float e_af = a_af * a_af, e_as = a_as * a_as, e_sf = a_sf * a_sf, e_ss = a_ss * a_ss;
    pw[8]  = e_af * e_af;  pw[9]  = e_as * e_as;   // a^4
    pw[10] = e_sf * e_sf;  pw[11] = e_ss * e_ss;
    pw[12] = (float)(-0.125 * slope);              // nhs_q (quad-avg input)
}

// Pass 1: 4x-decimated diagonal chunk maps at K ES-nodes, SUB snapshots/node.
// GUESSES ONLY (bias absorbed by exact Newton). One float4 = one q-step.
__global__ __launch_bounds__(256) void ssl_map(
        const float* __restrict__ x, __half2* __restrict__ mp,
        const float* __restrict__ pw, int B)
{
    int tid = blockIdx.x * 256 + threadIdx.x;
    int k  = tid & (K - 1);
    int bc = tid >> 4;                       // b*NCM + c
    if (bc >= B * NCM) return;
    int c  = bc & (NCM - 1);
    int b  = bc >> 6;                        // NCM = 64

    const float nhs_q = pw[12], hst = pw[1], nq = pw[2], r = pw[3];
    const float e_af = pw[8], e_as = pw[9], e_sf = pw[10], e_ss = pw[11];

    float v0s = -STEP_ES * (float)k;
    float EF = v0s, ES = v0s, Y = EF + ES;
    const float4* __restrict__ xr = reinterpret_cast<const float4*>(x + (size_t)b * T_LEN);
    const int v0 = c * (CM >> 2);            // 512 float4 per coarse chunk

    float4 buf[DPF];
    #pragma unroll
    for (int i = 0; i < DPF; ++i) buf[i] = xr[v0 + i];

    #pragma unroll 1
    for (int q16 = 0; q16 < SUB; ++q16) {
        const int s0 = v0 + q16 * (CF >> 2); // 32 float4 per sub-segment
        for (int v = s0; v < s0 + (CF >> 2); v += DPF) {
            #pragma unroll
            for (int i = 0; i < DPF; ++i) {
                float4 xv = buf[i];
                int nxt = v + DPF + i;
                if (nxt < NV_ROW) buf[i] = xr[nxt];
                float s = (xv.x + xv.y) + (xv.z + xv.w);
                float sx2 = fmaf(nhs_q, s, hst);
                float u2  = fmaf(nq, Y, sx2);
                float t2  = fminf(u2, 0.0f);
                bool att  = sx2 < r * Y;
                float af  = att ? e_af : e_sf;
                float as2 = att ? e_as : e_ss;
                EF = fmaf(af,  EF - t2, t2);
                ES = fmaf(as2, ES - t2, t2);
                Y  = EF + ES;
            }
        }
        mp[((size_t)bc * SUB + q16) * K + k] = __floats2half2_rn(EF, ES);
    }
}

// Pass 2: per-row block (1024 threads): link-stage -> compose0 -> 3x EXACT
// Newton (jac 1 chunk/thread + affine LDS scan) -> exact out.
__global__ __launch_bounds__(1024) void ssl_row(
        const float* __restrict__ x, float* __restrict__ out,
        const __half2* __restrict__ mp, const float* __restrict__ pw, int B)
{
    __shared__ __half2 link_s[LINK];                 // 4 KB
    __shared__ float2 bnd_s[NC];                     // 8 KB
    __shared__ float4 JA[NC], JB[NC];                // 16+16 KB
    __shared__ float2 GA[NC], GB[NC];                // 8+8 KB

    const int b = blockIdx.x;
    const int t = threadIdx.x;                       // 0..1023

    const float nhs = pw[0], hst = pw[1], nq = pw[2], r = pw[3];
    const float a_af = pw[4], a_as = pw[5], a_sf = pw[6], a_ss = pw[7];

    const float4* __restrict__ xr = reinterpret_cast<const float4*>(x + (size_t)b * T_LEN);

    // ---- stage link slice: last snapshot (q=SUB-1) of each coarse chunk ----
    {
        int c = t >> 4, k = t & 15;                  // t < LINK == 1024
        link_s[t] = mp[((size_t)(b * NCM + c) * SUB + (SUB - 1)) * K + k];
    }
    __syncthreads();

    // ---- compose0 serial: 64 coarse links on LDS (thread 0) ----
    if (t == 0) {
        float EF = 0.0f, ES = 0.0f;
        for (int c = 0; c < NCM; ++c) {
            bnd_s[SUB * c] = make_float2(EF, ES);
            float tt = -ES * INV_STEP;
            int idx = (int)tt;
            idx = idx < 0 ? 0 : (idx > K - 2 ? K - 2 : idx);
            float u = tt - (float)idx;
            float2 a0 = __half22float2(link_s[c * K + idx]);
            float2 a1 = __half22float2(link_s[c * K + idx + 1]);
            EF = a0.x + (a1.x - a0.x) * u;
            ES = a0.y + (a1.y - a0.y) * u;
        }
    }
    __syncthreads();
    // ---- parallel snapshot guesses at the other 15 boundaries per chunk ----
    {
        int c = t >> 4, j = t & 15;
        if (j > 0) {
            float ES = bnd_s[SUB * c].y;
            float tt = -ES * INV_STEP;
            int idx = (int)tt;
            idx = idx < 0 ? 0 : (idx > K - 2 ? K - 2 : idx);
            float u = tt - (float)idx;
            const __half2* m = mp + ((size_t)(b * NCM + c) * SUB + (j - 1)) * K;
            float2 a0 = __half22float2(m[idx]);
            float2 a1 = __half22float2(m[idx + 1]);
            bnd_s[t] = make_float2(a0.x + (a1.x - a0.x) * u,
                                   a0.y + (a1.y - a0.y) * u);
        }
    }
    __syncthreads();

    // ---- 3x EXACT Newton: jac (1 chunk/thread) -> affine scan ----
    #pragma unroll 1
    for (int it = 0; it < 3; ++it) {
        {
            float2 s0 = bnd_s[t];
            float EF = s0.x, ES = s0.y, Y = EF + ES;
            float jFx = 1.0f, jFy = 0.0f, jSx = 0.0f, jSy = 1.0f;
            const int v0 = t * (CF >> 2), v1 = v0 + (CF >> 2);   // 32 float4

            float4 buf[DPF];
            #pragma unroll
            for (int i = 0; i < DPF; ++i) buf[i] = xr[v0 + i];

            for (int v = v0; v < v1; v += DPF) {
                #pragma unroll
                for (int i = 0; i < DPF; ++i) {
                    float4 xv = buf[i];
                    int nxt = v + DPF + i;
                    if (nxt < NV_ROW) buf[i] = xr[nxt];
#define SSL_STEP_J(XV) { \
                    float sx2 = fmaf(nhs, (XV), hst); \
                    float u2  = fmaf(nq, Y, sx2); \
                    float t2  = fminf(u2, 0.0f); \
                    float m   = (u2 < 0.0f) ? nq : 0.0f; \
                    bool att  = sx2 < r * Y; \
                    float af  = att ? a_af : a_sf; \
                    float as2 = att ? a_as : a_ss; \
                    float jtx = m * (jFx + jSx); \
                    float jty = m * (jFy + jSy); \
                    jFx = fmaf(af,  jFx - jtx, jtx); \
                    jFy = fmaf(af,  jFy - jty, jty); \
                    jSx = fmaf(as2, jSx - jtx, jtx); \
                    jSy = fmaf(as2, jSy - jty, jty); \
                    EF  = fmaf(af,  EF - t2, t2); \
                    ES  = fmaf(as2, ES - t2, t2); \
                    Y   = EF + ES; }
                    SSL_STEP_J(xv.x)
                    SSL_STEP_J(xv.y)
                    SSL_STEP_J(xv.z)
                    SSL_STEP_J(xv.w)
#undef SSL_STEP_J
                }
            }
            JA[t] = make_float4(jFx, jFy, jSx, jSy);
            GA[t] = make_float2(EF - (jFx * s0.x + jFy * s0.y),
                                ES - (jSx * s0.x + jSy * s0.y));
        }
        __syncthreads();

        // Hillis-Steele inclusive scan of affine maps (later ∘ earlier).
        float4* Js = JA; float2* Gs = GA;
        float4* Jd = JB; float2* Gd = GB;
        #pragma unroll 1
        for (int d = 1; d < NC; d <<= 1) {
            float4 J = Js[t];
            float2 g = Gs[t];
            if (t >= d) {
                float4 Je = Js[t - d];
                float2 ge = Gs[t - d];
                float4 Jn;
                Jn.x = J.x * Je.x + J.y * Je.z;
                Jn.y = J.x * Je.y + J.y * Je.w;
                Jn.z = J.z * Je.x + J.w * Je.z;
                Jn.w = J.z * Je.y + J.w * Je.w;
                float2 gn;
                gn.x = J.x * ge.x + J.y * ge.y + g.x;
                gn.y = J.z * ge.x + J.w * ge.y + g.y;
                J = Jn; g = gn;
            }
            Jd[t] = J; Gd[t] = g;
            __syncthreads();
            float4* tJ = Js; Js = Jd; Jd = tJ;
            float2* tG = Gs; Gs = Gd; Gd = tG;
        }
        bnd_s[t] = (t == 0) ? make_float2(0.0f, 0.0f) : Gs[t - 1];
        __syncthreads();
    }

    // ---- out: exact rerun of each fine chunk, store y ----
    {
        float2 s = bnd_s[t];
        float EF = s.x, ES = s.y, Y = EF + ES;
        float4* __restrict__ yr = reinterpret_cast<float4*>(out + (size_t)b * T_LEN);
        const int v0 = t * (CF >> 2), v1 = v0 + (CF >> 2);

        float4 buf[DPF];
        #pragma unroll
        for (int i = 0; i < DPF; ++i) buf[i] = xr[v0 + i];

        for (int v = v0; v < v1; v += DPF) {
            #pragma unroll
            for (int i = 0; i < DPF; ++i) {
                float4 xv = buf[i];
                int nxt = v + DPF + i;
                if (nxt < NV_ROW) buf[i] = xr[nxt];
                float4 yo;
#define SSL_STEP(XV, YOUT) { \
                float sx2 = fmaf(nhs, (XV), hst); \
                float u2  = fmaf(nq, Y, sx2); \
                float t2  = fminf(u2, 0.0f); \
                bool att  = sx2 < r * Y; \
                float af  = att ? a_af : a_sf; \
                float as2 = att ? a_as : a_ss; \
                EF = fmaf(af,  EF - t2, t2); \
                ES = fmaf(as2, ES - t2, t2); \
                Y  = EF + ES; \
                (YOUT) = Y; }
                SSL_STEP(xv.x, yo.x)
                SSL_STEP(xv.y, yo.y)
                SSL_STEP(xv.z, yo.z)
                SSL_STEP(xv.w, yo.w)
#undef SSL_STEP
                yr[v + i] = yo;
            }
        }
    }
}

extern "C" void kernel_launch(void* const* d_in, const int* in_sizes, int n_in,
                              void* d_out, int out_size, void* d_ws, size_t ws_size,
                              hipStream_t stream) {
    const float* x = (const float*)d_in[0];
    const int B = in_sizes[0] / T_LEN;   // 128

    // ws: mp (B*NCM*SUB*K half2 = 8 MB, 16B-aligned at base) | pw (16 floats)
    __half2* mp = (__half2*)d_ws;
    float*   pw = (float*)(mp + (size_t)B * NCM * SUB * K);

    ssl_params_k<<<1, 1, 0, stream>>>(
        pw,
        (const float*)d_in[1], (const float*)d_in[2], (const float*)d_in[3],
        (const float*)d_in[4], (const float*)d_in[5], (const float*)d_in[6],
        (const float*)d_in[7]);

    int map_threads = B * NCM * K;       // 131072
    ssl_map<<<(map_threads + 255) / 256, 256, 0, stream>>>(x, mp, pw, B);

    ssl_row<<<B, 1024, 0, stream>>>(x, (float*)d_out, mp, pw, B);
}